// Round 1
// baseline (140.245 us; speedup 1.0000x reference)
//
#include <hip/hip_runtime.h>
#include <hip/hip_bf16.h>
#include <stdint.h>

#define NN 4096

typedef __attribute__((ext_vector_type(8))) __bf16 bf16x8;
typedef __attribute__((ext_vector_type(8))) short  s16x8;
typedef __attribute__((ext_vector_type(4))) float  f32x4;

// ---------------- conversion: Au = triu(A) as bf16, row-major [N][N] -------------
__global__ __launch_bounds__(256) void conv_mask_A(const float* __restrict__ A,
                                                   ushort* __restrict__ Au) {
    int idx = blockIdx.x * 256 + threadIdx.x;   // one 8-float group
    int row = idx >> 9;                         // 4096/8 = 512 groups per row
    int c0  = (idx & 511) << 3;
    const float* p = A + (size_t)row * NN + c0;
    f32x4 a0 = *reinterpret_cast<const f32x4*>(p);
    f32x4 a1 = *reinterpret_cast<const f32x4*>(p + 4);
    s16x8 o;
#pragma unroll
    for (int j = 0; j < 8; ++j) {
        float f = ((c0 + j) >= row) ? ((j < 4) ? a0[j] : a1[j - 4]) : 0.0f;
        uint32_t u = __builtin_bit_cast(uint32_t, f);
        u += 0x7fffu + ((u >> 16) & 1u);        // RNE to bf16
        o[j] = (short)(u >> 16);
    }
    *reinterpret_cast<s16x8*>(Au + (size_t)row * NN + c0) = o;
}

// -------- conversion: BTu[j][k] = (j>=k) ? bf16(B[k][j]) : 0  (masked transpose) --------
__global__ __launch_bounds__(256) void conv_mask_BT(const float* __restrict__ B,
                                                    ushort* __restrict__ BTu) {
    const int tr = blockIdx.y;   // k-tile of B (rows)
    const int tc = blockIdx.x;   // j-tile of B (cols) -> output rows
    const int tid = threadIdx.x;

    if (tc < tr) {               // j < k everywhere -> zeros
        s16x8 z = {0, 0, 0, 0, 0, 0, 0, 0};
#pragma unroll
        for (int q = 0; q < 8; ++q) {
            int c = q * 256 + tid;            // 2048 chunks of 8 elems
            int r = c >> 4, ch = c & 15;
            *reinterpret_cast<s16x8*>(BTu + (size_t)(tc * 128 + r) * NN + tr * 128 + ch * 8) = z;
        }
        return;
    }

    __shared__ ushort tile[128][136];
#pragma unroll
    for (int q = 0; q < 16; ++q) {
        int c = q * 256 + tid;                // 4096 float4 chunks
        int r = c >> 5, f4 = c & 31;
        const float* p = B + (size_t)(tr * 128 + r) * NN + tc * 128 + f4 * 4;
        f32x4 v = *reinterpret_cast<const f32x4*>(p);
#pragma unroll
        for (int j = 0; j < 4; ++j) {
            int col = f4 * 4 + j;
            float f = ((tc * 128 + col) >= (tr * 128 + r)) ? v[j] : 0.0f;
            uint32_t u = __builtin_bit_cast(uint32_t, f);
            u += 0x7fffu + ((u >> 16) & 1u);
            tile[r][col] = (ushort)(u >> 16);
        }
    }
    __syncthreads();
#pragma unroll
    for (int q = 0; q < 8; ++q) {
        int c = q * 256 + tid;                // 2048 output chunks
        int orow = c >> 4, ch = c & 15;       // orow = B col (output row), ch*8.. = k
        s16x8 o;
#pragma unroll
        for (int j = 0; j < 8; ++j) o[j] = (short)tile[ch * 8 + j][orow];
        *reinterpret_cast<s16x8*>(BTu + (size_t)(tc * 128 + orow) * NN + tr * 128 + ch * 8) = o;
    }
}

// ---------------- main MFMA kernel: 128x128 tile, BK=32, 4 waves ----------------
__global__ __launch_bounds__(256) void trimm_bf16(const ushort* __restrict__ Au,
                                                  const ushort* __restrict__ BTu,
                                                  float* __restrict__ C) {
    const int bi = blockIdx.y, bj = blockIdx.x;
    const int tid = threadIdx.x;

    if (bi > bj) {   // lower tile: zeros
        int r = tid >> 1, cb = (tid & 1) * 64;
        float* p = C + (size_t)(bi * 128 + r) * NN + bj * 128 + cb;
        f32x4 z = {0.f, 0.f, 0.f, 0.f};
#pragma unroll
        for (int v = 0; v < 16; ++v) *reinterpret_cast<f32x4*>(p + v * 4) = z;
        return;
    }

    __shared__ ushort lA[128 * 32];   // 8 KB
    __shared__ ushort lB[128 * 32];   // 8 KB (holds B^T rows)

    const int wid = tid >> 6, lane = tid & 63;
    const int wr = wid >> 1, wc = wid & 1;           // wave's 64x64 quadrant
    const int l16 = lane & 15, kh = lane >> 4;       // fragment coords

    f32x4 zero = {0.f, 0.f, 0.f, 0.f};
    f32x4 acc[4][4];
#pragma unroll
    for (int m = 0; m < 4; ++m)
#pragma unroll
        for (int n = 0; n < 4; ++n) acc[m][n] = zero;

    const int nkt = (bj - bi + 1) * 4;               // K-steps of 32 over [bi*128,(bj+1)*128)

    for (int kt = 0; kt < nkt; ++kt) {
        const int kk = bi * 128 + kt * 32;
        // stage A tile [128][32] and B^T tile [128][32]; linear LDS dest, 16B/lane
#pragma unroll
        for (int q = 0; q < 2; ++q) {
            int c = (wid * 2 + q) * 64 + lane;       // 16B chunk index, 512 per tile
            int row = c >> 2, c8 = (c & 3) << 3;
            const ushort* ga = Au  + (size_t)(bi * 128 + row) * NN + kk + c8;
            const ushort* gb = BTu + (size_t)(bj * 128 + row) * NN + kk + c8;
            __builtin_amdgcn_global_load_lds((__attribute__((address_space(1))) const void*)ga,
                                             (__attribute__((address_space(3))) void*)(&lA[(wid * 2 + q) * 512]),
                                             16, 0, 0);
            __builtin_amdgcn_global_load_lds((__attribute__((address_space(1))) const void*)gb,
                                             (__attribute__((address_space(3))) void*)(&lB[(wid * 2 + q) * 512]),
                                             16, 0, 0);
        }
        __syncthreads();

        bf16x8 af[4], bfr[4];
#pragma unroll
        for (int m = 0; m < 4; ++m)
            af[m] = *reinterpret_cast<const bf16x8*>(&lA[(wr * 64 + m * 16 + l16) * 32 + kh * 8]);
#pragma unroll
        for (int n = 0; n < 4; ++n)
            bfr[n] = *reinterpret_cast<const bf16x8*>(&lB[(wc * 64 + n * 16 + l16) * 32 + kh * 8]);

#pragma unroll
        for (int m = 0; m < 4; ++m)
#pragma unroll
            for (int n = 0; n < 4; ++n)
                acc[m][n] = __builtin_amdgcn_mfma_f32_16x16x32_bf16(af[m], bfr[n], acc[m][n], 0, 0, 0);

        __syncthreads();
    }

    // C/D layout: col = lane&15, row = (lane>>4)*4 + reg
#pragma unroll
    for (int m = 0; m < 4; ++m) {
#pragma unroll
        for (int n = 0; n < 4; ++n) {
            int row = bi * 128 + wr * 64 + m * 16 + kh * 4;
            int col = bj * 128 + wc * 64 + n * 16 + l16;
#pragma unroll
            for (int r = 0; r < 4; ++r)
                C[(size_t)(row + r) * NN + col] = acc[m][n][r];
        }
    }
}

// ---------------- fp32 fallback (only if ws too small) ----------------
__global__ __launch_bounds__(256) void tri_fp32(const float* __restrict__ A,
                                                const float* __restrict__ B,
                                                float* __restrict__ C) {
    const int bi = blockIdx.y, bj = blockIdx.x, tid = threadIdx.x;
    const int r0 = (tid >> 4) << 2, c0 = (tid & 15) << 2;
    f32x4 z = {0.f, 0.f, 0.f, 0.f};
    if (bi > bj) {
#pragma unroll
        for (int r = 0; r < 4; ++r)
            *reinterpret_cast<f32x4*>(C + (size_t)(bi * 64 + r0 + r) * NN + bj * 64 + c0) = z;
        return;
    }
    __shared__ float As[64][65], Bs[64][65];
    float acc[4][4] = {};
    for (int kt = bi; kt <= bj; ++kt) {
        const int k0 = kt * 64;
#pragma unroll
        for (int q = 0; q < 4; ++q) {
            int c = q * 256 + tid, r = c >> 4, f4 = c & 15;
            f32x4 va = *reinterpret_cast<const f32x4*>(A + (size_t)(bi * 64 + r) * NN + k0 + f4 * 4);
            f32x4 vb = *reinterpret_cast<const f32x4*>(B + (size_t)(k0 + r) * NN + bj * 64 + f4 * 4);
#pragma unroll
            for (int j = 0; j < 4; ++j) {
                As[r][f4 * 4 + j] = (k0 + f4 * 4 + j >= bi * 64 + r) ? va[j] : 0.f;
                Bs[r][f4 * 4 + j] = (bj * 64 + f4 * 4 + j >= k0 + r) ? vb[j] : 0.f;
            }
        }
        __syncthreads();
        for (int kk = 0; kk < 64; ++kk) {
#pragma unroll
            for (int r = 0; r < 4; ++r) {
                float a = As[r0 + r][kk];
#pragma unroll
                for (int cc = 0; cc < 4; ++cc) acc[r][cc] += a * Bs[kk][c0 + cc];
            }
        }
        __syncthreads();
    }
#pragma unroll
    for (int r = 0; r < 4; ++r) {
        f32x4 o = {acc[r][0], acc[r][1], acc[r][2], acc[r][3]};
        *reinterpret_cast<f32x4*>(C + (size_t)(bi * 64 + r0 + r) * NN + bj * 64 + c0) = o;
    }
}

extern "C" void kernel_launch(void* const* d_in, const int* in_sizes, int n_in,
                              void* d_out, int out_size, void* d_ws, size_t ws_size,
                              hipStream_t stream) {
    const float* A = (const float*)d_in[0];
    const float* B = (const float*)d_in[1];
    float* C = (float*)d_out;

    const size_t need = (size_t)2 * NN * NN * sizeof(ushort);   // 64 MB
    if (ws_size >= need) {
        ushort* Au  = (ushort*)d_ws;
        ushort* BTu = Au + (size_t)NN * NN;
        conv_mask_A<<<(NN * NN / 8) / 256, 256, 0, stream>>>(A, Au);
        conv_mask_BT<<<dim3(32, 32), 256, 0, stream>>>(B, BTu);
        trimm_bf16<<<dim3(32, 32), 256, 0, stream>>>(Au, BTu, C);
    } else {
        tri_fp32<<<dim3(64, 64), 256, 0, stream>>>(A, B, C);
    }
}

// Round 2
// 115.981 us; speedup vs baseline: 1.2092x; 1.2092x over previous
//
#include <hip/hip_runtime.h>
#include <hip/hip_bf16.h>
#include <stdint.h>

#define NN 4096

typedef __attribute__((ext_vector_type(8))) __bf16 bf16x8;
typedef __attribute__((ext_vector_type(8))) short  s16x8;
typedef __attribute__((ext_vector_type(4))) float  f32x4;

__device__ __forceinline__ ushort f2bf(float f) {
    uint32_t u = __builtin_bit_cast(uint32_t, f);
    u += 0x7fffu + ((u >> 16) & 1u);            // RNE to bf16
    return (ushort)(u >> 16);
}

// ---------- fused prep: z=0 conv A (triu, bf16), z=1 conv B^T (triu, bf16), z=2 zero C ----------
__global__ __launch_bounds__(256) void prep(const float* __restrict__ A,
                                            const float* __restrict__ B,
                                            ushort* __restrict__ Au,
                                            ushort* __restrict__ BTu,
                                            float* __restrict__ C) {
    const int role = blockIdx.z;
    const int tr = blockIdx.y;      // row tile (A row-block / B k-block / C row-block)
    const int tc = blockIdx.x;      // col tile
    const int tid = threadIdx.x;

    if (role == 0) {
        // Au[tr*128 + r][tc*128 + c] = (col >= row) ? bf16(A) : 0 ; lower tiles never read
        if (tc < tr) return;
        const bool diag = (tc == tr);
#pragma unroll
        for (int q = 0; q < 8; ++q) {
            int g = q * 256 + tid;              // 2048 groups of 8
            int r = g >> 4, c0 = (g & 15) << 3;
            int row = tr * 128 + r, col0 = tc * 128 + c0;
            const float* p = A + (size_t)row * NN + col0;
            f32x4 a0 = *reinterpret_cast<const f32x4*>(p);
            f32x4 a1 = *reinterpret_cast<const f32x4*>(p + 4);
            s16x8 o;
#pragma unroll
            for (int j = 0; j < 8; ++j) {
                float f = (j < 4) ? a0[j] : a1[j - 4];
                if (diag && (col0 + j) < row) f = 0.0f;
                o[j] = (short)f2bf(f);
            }
            *reinterpret_cast<s16x8*>(Au + (size_t)row * NN + col0) = o;
        }
        return;
    }

    if (role == 1) {
        // BTu[j][k] = (j >= k) ? bf16(B[k][j]) : 0 ; tr = k-tile, tc = j-tile; lower never read
        if (tc < tr) return;
        const bool diag = (tc == tr);
        __shared__ ushort tile[128][136];
#pragma unroll
        for (int q = 0; q < 16; ++q) {
            int g = q * 256 + tid;              // 4096 float4 groups
            int r = g >> 5, f4 = g & 31;
            int krow = tr * 128 + r;
            const float* p = B + (size_t)krow * NN + tc * 128 + f4 * 4;
            f32x4 v = *reinterpret_cast<const f32x4*>(p);
#pragma unroll
            for (int j = 0; j < 4; ++j) {
                int col = f4 * 4 + j;
                float f = v[j];
                if (diag && (tc * 128 + col) < krow) f = 0.0f;
                tile[r][col] = f2bf(f);
            }
        }
        __syncthreads();
#pragma unroll
        for (int q = 0; q < 8; ++q) {
            int g = q * 256 + tid;              // 2048 output chunks of 8
            int orow = g >> 4, ch = g & 15;
            s16x8 o;
#pragma unroll
            for (int j = 0; j < 8; ++j) o[j] = (short)tile[ch * 8 + j][orow];
            *reinterpret_cast<s16x8*>(BTu + (size_t)(tc * 128 + orow) * NN + tr * 128 + ch * 8) = o;
        }
        return;
    }

    // role 2: zero C tile if lower-tri OR multi-chunk upper tile (d >= 8, atomic-accumulated)
    {
        int d = tc - tr;
        bool need = (d < 0) || (d >= 8);
        if (!need) return;
        int r = tid >> 1, cb = (tid & 1) * 64;
        float* p = C + (size_t)(tr * 128 + r) * NN + tc * 128 + cb;
        f32x4 z = {0.f, 0.f, 0.f, 0.f};
#pragma unroll
        for (int v = 0; v < 16; ++v) *reinterpret_cast<f32x4*>(p + v * 4) = z;
    }
}

// ---------------- split-K MFMA kernel: 128x128 tile, BK=32, 4 waves, 1000 items ----------------
__global__ __launch_bounds__(256) void trimm_split(const ushort* __restrict__ Au,
                                                   const ushort* __restrict__ BTu,
                                                   float* __restrict__ C) {
    const int tid = threadIdx.x;

    // decode flat item id -> (bi, bj, chunk c of nch)
    int rem = blockIdx.x;
    int d = 0, nch = 1, bi = 0, c = 0;
    for (d = 0; d < 32; ++d) {
        int nc = (d >> 3) + 1;                 // ceil((d+1)/8)
        int cnt = (32 - d) * nc;
        if (rem < cnt) { bi = rem / nc; c = rem % nc; nch = nc; break; }
        rem -= cnt;
    }
    const int bj = bi + d;
    const int L = d + 1;                       // k-tiles of 128 in [bi, bj]
    const int kt0 = (c * L) / nch, kt1 = ((c + 1) * L) / nch;
    const int k_base = (bi + kt0) * 128;
    const int nsteps = (kt1 - kt0) * 4;        // K-steps of 32

    __shared__ ushort lA[128 * 32];
    __shared__ ushort lB[128 * 32];

    const int wid = tid >> 6, lane = tid & 63;
    const int wr = wid >> 1, wc = wid & 1;
    const int l16 = lane & 15, kh = lane >> 4;

    f32x4 zero = {0.f, 0.f, 0.f, 0.f};
    f32x4 acc[4][4];
#pragma unroll
    for (int m = 0; m < 4; ++m)
#pragma unroll
        for (int n = 0; n < 4; ++n) acc[m][n] = zero;

    for (int kt = 0; kt < nsteps; ++kt) {
        const int kk = k_base + kt * 32;
#pragma unroll
        for (int q = 0; q < 2; ++q) {
            int g = (wid * 2 + q) * 64 + lane;  // 512 16B chunks per tile
            int row = g >> 2, c8 = (g & 3) << 3;
            const ushort* ga = Au  + (size_t)(bi * 128 + row) * NN + kk + c8;
            const ushort* gb = BTu + (size_t)(bj * 128 + row) * NN + kk + c8;
            __builtin_amdgcn_global_load_lds((__attribute__((address_space(1))) const void*)ga,
                                             (__attribute__((address_space(3))) void*)(&lA[(wid * 2 + q) * 512]),
                                             16, 0, 0);
            __builtin_amdgcn_global_load_lds((__attribute__((address_space(1))) const void*)gb,
                                             (__attribute__((address_space(3))) void*)(&lB[(wid * 2 + q) * 512]),
                                             16, 0, 0);
        }
        __syncthreads();

        bf16x8 af[4], bfr[4];
#pragma unroll
        for (int m = 0; m < 4; ++m)
            af[m] = *reinterpret_cast<const bf16x8*>(&lA[(wr * 64 + m * 16 + l16) * 32 + kh * 8]);
#pragma unroll
        for (int n = 0; n < 4; ++n)
            bfr[n] = *reinterpret_cast<const bf16x8*>(&lB[(wc * 64 + n * 16 + l16) * 32 + kh * 8]);

#pragma unroll
        for (int m = 0; m < 4; ++m)
#pragma unroll
            for (int n = 0; n < 4; ++n)
                acc[m][n] = __builtin_amdgcn_mfma_f32_16x16x32_bf16(af[m], bfr[n], acc[m][n], 0, 0, 0);

        __syncthreads();
    }

    // C/D layout: col = lane&15, row = (lane>>4)*4 + reg
    if (nch == 1) {
#pragma unroll
        for (int m = 0; m < 4; ++m)
#pragma unroll
            for (int n = 0; n < 4; ++n) {
                int row = bi * 128 + wr * 64 + m * 16 + kh * 4;
                int col = bj * 128 + wc * 64 + n * 16 + l16;
#pragma unroll
                for (int r = 0; r < 4; ++r)
                    C[(size_t)(row + r) * NN + col] = acc[m][n][r];
            }
    } else {
#pragma unroll
        for (int m = 0; m < 4; ++m)
#pragma unroll
            for (int n = 0; n < 4; ++n) {
                int row = bi * 128 + wr * 64 + m * 16 + kh * 4;
                int col = bj * 128 + wc * 64 + n * 16 + l16;
#pragma unroll
                for (int r = 0; r < 4; ++r)
                    unsafeAtomicAdd(&C[(size_t)(row + r) * NN + col], acc[m][n][r]);
            }
    }
}

// ---------------- fp32 fallback (only if ws too small) ----------------
__global__ __launch_bounds__(256) void tri_fp32(const float* __restrict__ A,
                                                const float* __restrict__ B,
                                                float* __restrict__ C) {
    const int bi = blockIdx.y, bj = blockIdx.x, tid = threadIdx.x;
    const int r0 = (tid >> 4) << 2, c0 = (tid & 15) << 2;
    f32x4 z = {0.f, 0.f, 0.f, 0.f};
    if (bi > bj) {
#pragma unroll
        for (int r = 0; r < 4; ++r)
            *reinterpret_cast<f32x4*>(C + (size_t)(bi * 64 + r0 + r) * NN + bj * 64 + c0) = z;
        return;
    }
    __shared__ float As[64][65], Bs[64][65];
    float acc[4][4] = {};
    for (int kt = bi; kt <= bj; ++kt) {
        const int k0 = kt * 64;
#pragma unroll
        for (int q = 0; q < 4; ++q) {
            int g = q * 256 + tid, r = g >> 4, f4 = g & 15;
            f32x4 va = *reinterpret_cast<const f32x4*>(A + (size_t)(bi * 64 + r) * NN + k0 + f4 * 4);
            f32x4 vb = *reinterpret_cast<const f32x4*>(B + (size_t)(k0 + r) * NN + bj * 64 + f4 * 4);
#pragma unroll
            for (int j = 0; j < 4; ++j) {
                As[r][f4 * 4 + j] = (k0 + f4 * 4 + j >= bi * 64 + r) ? va[j] : 0.f;
                Bs[r][f4 * 4 + j] = (bj * 64 + f4 * 4 + j >= k0 + r) ? vb[j] : 0.f;
            }
        }
        __syncthreads();
        for (int kk = 0; kk < 64; ++kk) {
#pragma unroll
            for (int r = 0; r < 4; ++r) {
                float a = As[r0 + r][kk];
#pragma unroll
                for (int cc = 0; cc < 4; ++cc) acc[r][cc] += a * Bs[kk][c0 + cc];
            }
        }
        __syncthreads();
    }
#pragma unroll
    for (int r = 0; r < 4; ++r) {
        f32x4 o = {acc[r][0], acc[r][1], acc[r][2], acc[r][3]};
        *reinterpret_cast<f32x4*>(C + (size_t)(bi * 64 + r0 + r) * NN + bj * 64 + c0) = o;
    }
}

extern "C" void kernel_launch(void* const* d_in, const int* in_sizes, int n_in,
                              void* d_out, int out_size, void* d_ws, size_t ws_size,
                              hipStream_t stream) {
    const float* A = (const float*)d_in[0];
    const float* B = (const float*)d_in[1];
    float* C = (float*)d_out;

    const size_t need = (size_t)2 * NN * NN * sizeof(ushort);   // 64 MB
    if (ws_size >= need) {
        ushort* Au  = (ushort*)d_ws;
        ushort* BTu = Au + (size_t)NN * NN;
        prep<<<dim3(32, 32, 3), 256, 0, stream>>>(A, B, Au, BTu, C);
        trimm_split<<<1000, 256, 0, stream>>>(Au, BTu, C);
    } else {
        tri_fp32<<<dim3(64, 64), 256, 0, stream>>>(A, B, C);
    }
}